// Round 24
// baseline (1126.087 us; speedup 1.0000x reference)
//
#include <hip/hip_runtime.h>
#include <hip/hip_bf16.h>
#include <math.h>

// Problem constants
#define B_   256
#define NP_  3
#define LAT_ 512
#define TXT_ 768
#define D_   768
#define NL_  6
#define DI_  1536
#define DS_  16
#define DC_  4
#define DTR_ 48
#define L_   5
#define M_   (B_*L_)
#define EPS_ 1e-5f

// ---------------- workspace layout (BYTE offsets) ----------------
#define OB_WBF    0ull
#define OB_XPP    139591680ull
#define OB_TEMB   144310272ull
#define OB_ZNORM  144703488ull
#define OB_XBF    145883136ull
#define OB_TCBF   147849216ull
#define OB_CAT1   148242432ull
#define OB_XTBF   152174592ull
#define OB_XZBF   154140672ull
#define OB_UCY    169869312ull
#define OB_CAT2   177733632ull
#define OB_X      181665792ull
#define OB_TC     185597952ull
#define OB_ZFEAT  187170816ull   // zfeat f32 (dead after embed) -> tcf6 bf16 [6][256][768]
#define OB_XO     189530112ull
#define OB_PART   193462272ull

// bf16 weight arena element offsets
#define WO_LOCAL  0u
#define WO_F      3538944u
#define WO_FUSE   10616832u
#define WO_FINAL  17694720u
#define WO_IN     24772608u
#define WO_OUT    53084160u
#define WO_ZIN    67239936u
#define WO_TIN    67633152u
#define WO_TIME   68222976u
#define WO_ZOUT   68812800u
#define WO_ZNOISY 69206016u
#define WO_TEXT   69599232u
#define WO_END    69795840u
// NOTE: WO_END = 68160 waves * 1024 exactly -> no partial waves in cvt.

// prep kernel block partition
#define CVT_BLOCKS  17040u
#define XPAD_BLOCKS 1152u
#define TEMB_BLOCKS 384u
#define PREP_BLOCKS (CVT_BLOCKS + XPAD_BLOCKS + TEMB_BLOCKS)

typedef __attribute__((ext_vector_type(4))) float floatx4;
typedef __attribute__((ext_vector_type(8))) short short8;
typedef __attribute__((ext_vector_type(8))) unsigned short ushort8v;
typedef __attribute__((ext_vector_type(4))) unsigned short ushort4v;

__device__ __forceinline__ float sigm(float v) { return 1.f / (1.f + expf(-v)); }
__device__ __forceinline__ float softplus(float v) {
    return fmaxf(v, 0.f) + log1pf(expf(-fabsf(v)));
}
__device__ __forceinline__ unsigned short bf16rn(float f) {
    unsigned int u = __builtin_bit_cast(unsigned int, f);
    u = (u + 0x7fffu + ((u >> 16) & 1u)) >> 16;
    return (unsigned short)u;
}
__device__ __forceinline__ float b2f(unsigned short u) {
    unsigned int x = ((unsigned int)u) << 16;
    return __builtin_bit_cast(float, x);
}

template<int N> __device__ __forceinline__ void waitv() {
    asm volatile("s_waitcnt vmcnt(%0)" :: "i"(N) : "memory");
}

// ---------------- prep: cvt (batched NT loads) + xpad + temb in ONE launch ----------
struct CvtArgs { const float* s[12]; };

__global__ __launch_bounds__(256) void prep_kernel(
    CvtArgs a, unsigned short* __restrict__ dst,
    const float* __restrict__ xw, unsigned short* __restrict__ xpd,
    const int* __restrict__ ts, unsigned short* __restrict__ temb)
{
    unsigned bid = blockIdx.x;
    if (bid < CVT_BLOCKS) {
        constexpr unsigned ends[12] = {
            3538944u, 10616832u, 17694720u, 24772608u, 53084160u, 67239936u,
            67633152u, 68222976u, 68812800u, 69206016u, 69599232u, 69795840u };
        const unsigned wv = (bid * 256u + threadIdx.x) >> 6;
        const unsigned lane = threadIdx.x & 63u;
        const unsigned wbase = wv * 1024u;
        unsigned idxq[4];
        floatx4 v[4];
#pragma unroll
        for (int q = 0; q < 4; ++q) {
            unsigned gbase = wbase + (unsigned)q * 256u;
            int t = 0;
            while (gbase >= ends[t]) ++t;
            unsigned start = t ? ends[t - 1] : 0u;
            idxq[q] = gbase + lane * 4u;
            v[q] = __builtin_nontemporal_load((const floatx4*)(a.s[t] + (idxq[q] - start)));
        }
#pragma unroll
        for (int q = 0; q < 4; ++q) {
            ushort4v o = { bf16rn(v[q][0]), bf16rn(v[q][1]), bf16rn(v[q][2]), bf16rn(v[q][3]) };
            __builtin_nontemporal_store(o, (ushort4v*)(dst + idxq[q]));
        }
    } else if (bid < CVT_BLOCKS + XPAD_BLOCKS) {
        unsigned i8 = ((bid - CVT_BLOCKS) * 256u + threadIdx.x) * 8u;
        if (i8 >= 12u * 128u * 1536u) return;
        unsigned pi = i8 / (128u * 1536u);
        unsigned rem = i8 - pi * 128u * 1536u;
        unsigned row = rem / 1536u, col = rem - row * 1536u;
        ushort8v o = {0, 0, 0, 0, 0, 0, 0, 0};
        if (row < 80u) {
            const float* s = xw + ((size_t)pi * 80u + row) * 1536u + col;
            floatx4 v0 = __builtin_nontemporal_load((const floatx4*)s);
            floatx4 v1 = __builtin_nontemporal_load((const floatx4*)(s + 4));
            o = ushort8v{ bf16rn(v0[0]), bf16rn(v0[1]), bf16rn(v0[2]), bf16rn(v0[3]),
                          bf16rn(v1[0]), bf16rn(v1[1]), bf16rn(v1[2]), bf16rn(v1[3]) };
        }
        *(ushort8v*)(xpd + i8) = o;
    } else {
        int idx = (bid - CVT_BLOCKS - XPAD_BLOCKS) * 256 + threadIdx.x;
        if (idx >= B_ * 384) return;
        int j = idx % 384, b = idx / 384;
        float f = expf(-logf(10000.f) * (float)j / 384.f);
        float targ = (float)ts[b] * f;
        temb[(size_t)b * D_ + j]       = bf16rn(cosf(targ));
        temb[(size_t)b * D_ + 384 + j] = bf16rn(sinf(targ));
    }
}

// ============ bf16 MFMA GEMM (256 thr), DEPTH pipeline, counted vmcnt ============
// 64x64 DEPTH=4/PF=2: xproj (>256-block grid, co-residency).
template<int BM, int BN, int CD, int DEPTH, int PF>
__global__ __launch_bounds__(256) void gemm_bf16_kernel(
    const unsigned short* __restrict__ A, int lda,
    const unsigned short* __restrict__ W, int wld,
    const float* __restrict__ bias,
    const float* __restrict__ aux0,
    const float* __restrict__ aux1,
    void* __restrict__ Cv, int ldc,
    int M, int N, int K, int epi, int ncap,
    int zsplit, unsigned long long zA, unsigned long long zW, unsigned long long zC)
{
    constexpr int GA = BM / 64;
    constexpr int GB = BN / 64;
    constexpr int LPS = GA + GB;
    constexpr int FRM = BM / 32;
    constexpr int FRN = BN / 32;
    constexpr int BMSK = DEPTH - 1;

    const int z = blockIdx.z;
    const int dirz = z / zsplit, ksz = z - dirz * zsplit;
    A += (unsigned long long)dirz * zA + (unsigned long long)ksz * (unsigned)K;
    W += (unsigned long long)dirz * zW + (unsigned long long)ksz * (unsigned)K;

    __shared__ unsigned short lds[DEPTH][(BM + BN) * 32];

    const int tid = threadIdx.x;
    const int m0 = blockIdx.y * BM, n0 = blockIdx.x * BN;
    const int w = tid >> 6, lane = tid & 63;
    const int wr = w >> 1, wc = w & 1;
    const int lrow = lane & 15;
    const int lk = (lane >> 4) << 3;

    const int rA = tid >> 2, sA = tid & 3;
    const int scA = ((sA ^ ((rA >> 1) & 3)) << 3);
    floatx4 acc[FRM][FRN] = {};

    auto stage = [&](int buf, int k0) {
        unsigned short* base = &lds[buf][0];
#pragma unroll
        for (int i = 0; i < GA; ++i) {
            int t = tid + i * 256;
            int r = t >> 2;
            const unsigned short* src = A + (size_t)(m0 + r) * lda + k0 + scA;
            __builtin_amdgcn_global_load_lds(
                (const __attribute__((address_space(1))) unsigned int*)(const void*)src,
                (__attribute__((address_space(3))) unsigned int*)(void*)(base + i * 2048 + w * 512),
                16, 0, 0);
        }
#pragma unroll
        for (int i = 0; i < GB; ++i) {
            int t = tid + i * 256;
            int r = t >> 2;
            const unsigned short* src = W + (size_t)(n0 + r) * wld + k0 + scA;
            __builtin_amdgcn_global_load_lds(
                (const __attribute__((address_space(1))) unsigned int*)(const void*)src,
                (__attribute__((address_space(3))) unsigned int*)(void*)(base + BM * 32 + i * 2048 + w * 512),
                16, 0, 0);
        }
    };

    const int nt = K >> 5;
#pragma unroll
    for (int s = 0; s < PF; ++s)
        if (s < nt) stage(s, s << 5);

    int offA[FRM], offB[FRN];
#pragma unroll
    for (int i = 0; i < FRM; ++i) {
        int row = wr * (BM / 2) + i * 16 + lrow;
        offA[i] = row * 32 + (lk ^ (((row >> 1) & 3) << 3));
    }
#pragma unroll
    for (int j = 0; j < FRN; ++j) {
        int row = wc * (BN / 2) + j * 16 + lrow;
        offB[j] = BM * 32 + row * 32 + (lk ^ (((row >> 1) & 3) << 3));
    }

    for (int t = 0; t < nt; ++t) {
        int rem = nt - 1 - t;
        if (rem >= PF) { stage((t + PF) & BMSK, (t + PF) << 5); waitv<PF * LPS>(); }
        else if (rem == 5) waitv<5 * LPS>();
        else if (rem == 4) waitv<4 * LPS>();
        else if (rem == 3) waitv<3 * LPS>();
        else if (rem == 2) waitv<2 * LPS>();
        else if (rem == 1) waitv<1 * LPS>();
        else               waitv<0>();
        __builtin_amdgcn_s_barrier();
        const unsigned short* pl = &lds[t & BMSK][0];
        short8 af[FRM], bfv[FRN];
#pragma unroll
        for (int i = 0; i < FRM; ++i) af[i] = *(const short8*)(pl + offA[i]);
#pragma unroll
        for (int j = 0; j < FRN; ++j) bfv[j] = *(const short8*)(pl + offB[j]);
#pragma unroll
        for (int i = 0; i < FRM; ++i)
#pragma unroll
            for (int j = 0; j < FRN; ++j)
                acc[i][j] = __builtin_amdgcn_mfma_f32_16x16x32_bf16(af[i], bfv[j], acc[i][j], 0, 0, 0);
    }

#pragma unroll
    for (int i = 0; i < FRM; ++i) {
        int row0 = m0 + wr * (BM / 2) + i * 16 + (lane >> 4) * 4;
#pragma unroll
        for (int j = 0; j < FRN; ++j) {
            int col = n0 + wc * (BN / 2) + j * 16 + lrow;
            if (col >= ncap) continue;
            float bb = bias ? bias[col] : 0.f;
#pragma unroll
            for (int r = 0; r < 4; ++r) {
                int row = row0 + r;
                float v = acc[i][j][r] + bb;
                if (epi == 1) {
                    v = v * sigm(v);
                } else if (epi == 3) {
                    int b = row / 5;
                    v = acc[i][j][r] + bb + b2f(((const unsigned short*)aux0)[(size_t)b * 768 + col]);
                    v = aux1[(size_t)b * 768 + col] * sigm(v);
                }
                size_t off = (size_t)z * zC + (size_t)row * ldc + col;
                if (CD == 1) ((float*)Cv)[off] = v;
                else         ((unsigned short*)Cv)[off] = bf16rn(v);
            }
        }
    }
}

// ============ 512-thr 64x64 PARITY-SPLIT GEMM (R24) ============
// 8 waves = 4 quadrants (32x32) x 2 K-parities. Each wave computes only its parity's
// K-steps with a 2x2 fragment tile: 4 ds_read_b128 per 4 MFMA (1.0 ratio vs R21's
// 1.5) -> 33% less LDS-read traffic at identical staging/barrier/vmcnt structure.
// Parity partials merged via one 16KB LDS reduction (2 barriers) in the epilogue.
// All K at these sites are even multiples of 32 -> parity work is balanced.
template<int CD, int DEPTH, int PF>
__global__ __launch_bounds__(512) void gemm512p_kernel(
    const unsigned short* __restrict__ A, int lda,
    const unsigned short* __restrict__ W, int wld,
    const float* __restrict__ bias,
    const float* __restrict__ aux0,
    const float* __restrict__ aux1,
    void* __restrict__ Cv, int ldc,
    int M, int N, int K, int epi, int ncap,
    int zsplit, unsigned long long zA, unsigned long long zW, unsigned long long zC)
{
    constexpr int BMSK = DEPTH - 1;
    const int z = blockIdx.z;
    const int dirz = z / zsplit, ksz = z - dirz * zsplit;
    A += (unsigned long long)dirz * zA + (unsigned long long)ksz * (unsigned)K;
    W += (unsigned long long)dirz * zW + (unsigned long long)ksz * (unsigned)K;

    __shared__ unsigned short lds[DEPTH][128 * 32];   // 64KB

    const int tid = threadIdx.x;
    const int m0 = blockIdx.y * 64, n0 = blockIdx.x * 64;
    const int w = tid >> 6, lane = tid & 63;
    const int q = w & 3, p = w >> 2;                  // quadrant, K-parity
    const int qr = q >> 1, qc = q & 1;
    const int lrow = lane & 15;
    const int lk = (lane >> 4) << 3;

    const int st = tid & 255;
    const int rA = st >> 2, sA = st & 3;
    const int scA = ((sA ^ ((rA >> 1) & 3)) << 3);
    const bool isA = (tid < 256);
    floatx4 acc[2][2] = {};

    auto stage = [&](int buf, int k0) {
        unsigned short* dstp = &lds[buf][0] + (isA ? w * 512 : 2048 + (w - 4) * 512);
        const unsigned short* src = isA
            ? A + (size_t)(m0 + rA) * lda + k0 + scA
            : W + (size_t)(n0 + rA) * wld + k0 + scA;
        __builtin_amdgcn_global_load_lds(
            (const __attribute__((address_space(1))) unsigned int*)(const void*)src,
            (__attribute__((address_space(3))) unsigned int*)(void*)dstp,
            16, 0, 0);
    };

    const int nt = K >> 5;
#pragma unroll
    for (int s = 0; s < PF; ++s)
        if (s < nt) stage(s, s << 5);

    int offA[2], offB[2];
#pragma unroll
    for (int i = 0; i < 2; ++i) {
        int row = qr * 32 + i * 16 + lrow;
        offA[i] = row * 32 + (lk ^ (((row >> 1) & 3) << 3));
    }
#pragma unroll
    for (int j = 0; j < 2; ++j) {
        int row = qc * 32 + j * 16 + lrow;
        offB[j] = 2048 + row * 32 + (lk ^ (((row >> 1) & 3) << 3));
    }

    for (int t = 0; t < nt; ++t) {
        int rem = nt - 1 - t;
        if (rem >= PF) { stage((t + PF) & BMSK, (t + PF) << 5); waitv<PF>(); }
        else if (rem == 5) waitv<5>();
        else if (rem == 4) waitv<4>();
        else if (rem == 3) waitv<3>();
        else if (rem == 2) waitv<2>();
        else if (rem == 1) waitv<1>();
        else               waitv<0>();
        __builtin_amdgcn_s_barrier();
        if ((t & 1) == p) {
            const unsigned short* pl = &lds[t & BMSK][0];
            short8 a0 = *(const short8*)(pl + offA[0]);
            short8 a1 = *(const short8*)(pl + offA[1]);
            short8 b0 = *(const short8*)(pl + offB[0]);
            short8 b1 = *(const short8*)(pl + offB[1]);
            acc[0][0] = __builtin_amdgcn_mfma_f32_16x16x32_bf16(a0, b0, acc[0][0], 0, 0, 0);
            acc[0][1] = __builtin_amdgcn_mfma_f32_16x16x32_bf16(a0, b1, acc[0][1], 0, 0, 0);
            acc[1][0] = __builtin_amdgcn_mfma_f32_16x16x32_bf16(a1, b0, acc[1][0], 0, 0, 0);
            acc[1][1] = __builtin_amdgcn_mfma_f32_16x16x32_bf16(a1, b1, acc[1][1], 0, 0, 0);
        }
    }

    // parity reduction: p=1 waves park partials in LDS, p=0 waves add.
    __syncthreads();
    floatx4* red = (floatx4*)&lds[0][0];              // 4 quads x 256 floatx4 = 16KB
    if (p == 1) {
#pragma unroll
        for (int i = 0; i < 2; ++i)
#pragma unroll
            for (int j = 0; j < 2; ++j)
                red[q * 256 + lane * 4 + i * 2 + j] = acc[i][j];
    }
    __syncthreads();
    if (p == 0) {
#pragma unroll
        for (int i = 0; i < 2; ++i) {
            int row0 = m0 + qr * 32 + i * 16 + (lane >> 4) * 4;
#pragma unroll
            for (int j = 0; j < 2; ++j) {
                int col = n0 + qc * 32 + j * 16 + lrow;
                if (col >= ncap) continue;
                floatx4 sum = acc[i][j] + red[q * 256 + lane * 4 + i * 2 + j];
                float bb = bias ? bias[col] : 0.f;
#pragma unroll
                for (int r = 0; r < 4; ++r) {
                    int row = row0 + r;
                    float v = sum[r] + bb;
                    if (epi == 1) {
                        v = v * sigm(v);
                    } else if (epi == 3) {
                        int b = row / 5;
                        v = sum[r] + bb + b2f(((const unsigned short*)aux0)[(size_t)b * 768 + col]);
                        v = aux1[(size_t)b * 768 + col] * sigm(v);
                    }
                    size_t off = (size_t)z * zC + (size_t)row * ldc + col;
                    if (CD == 1) ((float*)Cv)[off] = v;
                    else         ((unsigned short*)Cv)[off] = bf16rn(v);
                }
            }
        }
    }
}

// ============ 512-thread 128x128 GEMM (R23, in_proj): 8 waves/block, 16 waves/CU ======
template<int DEPTH, int PF>
__global__ __launch_bounds__(512) void gemm512b_kernel(
    const unsigned short* __restrict__ A, int lda,
    const unsigned short* __restrict__ W, int wld,
    unsigned short* __restrict__ C, int ldc, int K)
{
    constexpr int BMSK = DEPTH - 1;
    __shared__ unsigned short lds[DEPTH][8192];

    const int tid = threadIdx.x;
    const int m0 = blockIdx.y * 128, n0 = blockIdx.x * 128;
    const int w = tid >> 6, lane = tid & 63;
    const int wr = w >> 2, wc = w & 3;          // 2 x 4 waves; wave-tile 64x32
    const int lrow = lane & 15;
    const int lk = (lane >> 4) << 3;

    const int rA = tid >> 2, sA = tid & 3;      // 128 rows x 4 slots
    const int scA = ((sA ^ ((rA >> 1) & 3)) << 3);
    floatx4 acc[4][2] = {};

    auto stage = [&](int buf, int k0) {
        unsigned short* base = &lds[buf][0];
        const unsigned short* srcA = A + (size_t)(m0 + rA) * lda + k0 + scA;
        __builtin_amdgcn_global_load_lds(
            (const __attribute__((address_space(1))) unsigned int*)(const void*)srcA,
            (__attribute__((address_space(3))) unsigned int*)(void*)(base + w * 512),
            16, 0, 0);
        const unsigned short* srcB = W + (size_t)(n0 + rA) * wld + k0 + scA;
        __builtin_amdgcn_global_load_lds(
            (const __attribute__((address_space(1))) unsigned int*)(const void*)srcB,
            (__attribute__((address_space(3))) unsigned int*)(void*)(base + 4096 + w * 512),
            16, 0, 0);
    };

    const int nt = K >> 5;
#pragma unroll
    for (int s = 0; s < PF; ++s)
        if (s < nt) stage(s, s << 5);

    int offA[4], offB[2];
#pragma unroll
    for (int i = 0; i < 4; ++i) {
        int row = wr * 64 + i * 16 + lrow;
        offA[i] = row * 32 + (lk ^ (((row >> 1) & 3) << 3));
    }
#pragma unroll
    for (int j = 0; j < 2; ++j) {
        int row = wc * 32 + j * 16 + lrow;
        offB[j] = 4096 + row * 32 + (lk ^ (((row >> 1) & 3) << 3));
    }

    for (int t = 0; t < nt; ++t) {
        int rem = nt - 1 - t;
        if (rem >= PF) { stage((t + PF) & BMSK, (t + PF) << 5); waitv<PF * 2>(); }
        else if (rem == 1) waitv<2>();
        else               waitv<0>();
        __builtin_amdgcn_s_barrier();
        const unsigned short* pl = &lds[t & BMSK][0];
        short8 af[4], bfv[2];
#pragma unroll
        for (int i = 0; i < 4; ++i) af[i] = *(const short8*)(pl + offA[i]);
#pragma unroll
        for (int j = 0; j < 2; ++j) bfv[j] = *(const short8*)(pl + offB[j]);
#pragma unroll
        for (int i = 0; i < 4; ++i)
#pragma unroll
            for (int j = 0; j < 2; ++j)
                acc[i][j] = __builtin_amdgcn_mfma_f32_16x16x32_bf16(af[i], bfv[j], acc[i][j], 0, 0, 0);
    }

#pragma unroll
    for (int i = 0; i < 4; ++i) {
        int row0 = m0 + wr * 64 + i * 16 + (lane >> 4) * 4;
#pragma unroll
        for (int j = 0; j < 2; ++j) {
            int col = n0 + wc * 32 + j * 16 + lrow;
#pragma unroll
            for (int r = 0; r < 4; ++r)
                C[(size_t)(row0 + r) * ldc + col] = bf16rn(acc[i][j][r]);
        }
    }
}

// ---------------- scatter z_feat + part_emb, add PE, write x/x_bf/tc/tc_bf -------
__global__ void finalize_embed_kernel(float* __restrict__ x,
                                      unsigned short* __restrict__ xbf,
                                      const float* __restrict__ zfeat,
                                      const float* __restrict__ part_emb,
                                      float* __restrict__ tc,
                                      unsigned short* __restrict__ tcbf)
{
    int idx = blockIdx.x * blockDim.x + threadIdx.x;
    if (idx >= B_ * L_ * D_) return;
    int d = idx % D_;
    int bl = idx / D_;
    int l = bl % L_, b = bl / L_;
    float v;
    if (l >= 2) v = zfeat[((size_t)(b * 3 + (l - 2))) * D_ + d] + part_emb[(size_t)(l - 2) * D_ + d];
    else        v = x[idx];
    int j = d >> 1;
    float dv = expf((float)(2 * j) * (-logf(10000.f) / (float)D_));
    float ang = (float)l * dv;
    v += (d & 1) ? cosf(ang) : sinf(ang);
    x[idx] = v;
    xbf[idx] = bf16rn(v);
    if (l == 1) { tc[(size_t)b * D_ + d] = v; tcbf[(size_t)b * D_ + d] = bf16rn(v); }
}

// ---------------- vectorized conv (8 ch/thread) + SiLU -> ucy bf16 ----------------
__global__ __launch_bounds__(256) void conv_silu_kernel(
    const unsigned short* __restrict__ xz,
    const float* __restrict__ cw,
    const float* __restrict__ cb,
    unsigned short* __restrict__ ucy)
{
    int idx = blockIdx.x * 256 + threadIdx.x;          // over 2*M*DI/8
    if (idx >= 2 * M_ * DI_ / 8) return;
    int c8 = (idx % (DI_ / 8)) * 8;
    int t2 = idx / (DI_ / 8);
    int bl = t2 % M_, dir = t2 / M_;
    int l = bl % L_, b = bl / L_;

    float acc[8];
    const float* cbp = cb + dir * DI_ + c8;
#pragma unroll
    for (int e = 0; e < 8; ++e) acc[e] = cbp[e];
    floatx4 w[8];
#pragma unroll
    for (int e = 0; e < 8; ++e)
        w[e] = *(const floatx4*)(cw + ((size_t)(dir * DI_ + c8 + e)) * DC_);
#pragma unroll
    for (int k = 0; k < DC_; ++k) {
        int lp = dir ? (l + 3 - k) : (l + k - 3);
        if (lp >= 0 && lp < L_) {
            ushort8v xv = *(const ushort8v*)(xz + ((size_t)(b * L_ + lp)) * 6144 + dir * 3072 + c8);
#pragma unroll
            for (int e = 0; e < 8; ++e) acc[e] = fmaf(w[e][k], b2f(xv[e]), acc[e]);
        }
    }
    ushort8v o;
#pragma unroll
    for (int e = 0; e < 8; ++e) { float v = acc[e]; o[e] = bf16rn(v * sigm(v)); }
    *(ushort8v*)(ucy + (size_t)idx * 8) = o;
}

// ---------------- fused: split-K reduce + dt-proj + softplus + scan + gate ----------
__global__ __launch_bounds__(256) void dtscan_kernel(
    const float* __restrict__ part,
    unsigned short* ucy,
    const unsigned short* __restrict__ xz,
    const float* __restrict__ dt_w,
    const float* __restrict__ dt_b,
    const float* __restrict__ Alog,
    const float* __restrict__ Dp)
{
    __shared__ float xd[L_][80];
    const int dir = blockIdx.z;
    const int b = blockIdx.y;
    const int ch = blockIdx.x * 256 + threadIdx.x;

    for (int o = threadIdx.x; o < L_ * 80; o += 256) {
        int l = o / 80, n = o - l * 80;
        float s = 0.f;
#pragma unroll
        for (int ks = 0; ks < 8; ++ks)
            s += part[((size_t)(dir * 8 + ks) * M_ + b * L_ + l) * 80 + n];
        xd[l][n] = s;
    }
    __syncthreads();

    const int cg = dir * DI_ + ch;
    float dt[L_];
    const float* wp = dt_w + (size_t)cg * DTR_;
    float dbv = dt_b[cg];
#pragma unroll
    for (int l = 0; l < L_; ++l) {
        float v = dbv;
#pragma unroll
        for (int r = 0; r < DTR_; ++r) v = fmaf(xd[l][r], wp[r], v);
        dt[l] = softplus(v);
    }

    float Aa[DS_], h[DS_];
#pragma unroll
    for (int s = 0; s < DS_; ++s) { Aa[s] = -expf(Alog[(size_t)cg * DS_ + s]); h[s] = 0.f; }
    float Dv = Dp[cg];

#pragma unroll
    for (int t = 0; t < L_; ++t) {
        const int l = dir ? (L_ - 1 - t) : t;
        size_t base = (size_t)(b * L_ + l);
        size_t uoff = ((size_t)dir * M_ + base) * DI_ + ch;
        float dtv = dt[l];
        float ucv = b2f(ucy[uoff]);
        float du = dtv * ucv;
        float y = 0.f;
#pragma unroll
        for (int s = 0; s < DS_; ++s) {
            h[s] = h[s] * expf(dtv * Aa[s]) + du * xd[l][48 + s];
            y = fmaf(h[s], xd[l][64 + s], y);
        }
        float zv = b2f(xz[base * 6144 + dir * 3072 + 1536 + ch]);
        ucy[uoff] = bf16rn((y + Dv * ucv) * (zv * sigm(zv)));
    }
}

// ---------------- block reduce helper ----------------
__device__ __forceinline__ float block_sum(float v)
{
    __shared__ float sd[4];
#pragma unroll
    for (int o = 1; o < 64; o <<= 1) v += __shfl_xor(v, o, 64);
    int lane = threadIdx.x & 63, wid = threadIdx.x >> 6;
    if (lane == 0) sd[wid] = v;
    __syncthreads();
    v = sd[0] + sd[1] + sd[2] + sd[3];
    __syncthreads();
    return v;
}

// LN(xo + x) -> x, xbf. If do_out and row%5>=2: second LN with oln params -> znorm.
__global__ __launch_bounds__(256) void ln_residual_kernel(
    const float* __restrict__ xo, float* __restrict__ x,
    unsigned short* __restrict__ xbf,
    const float* __restrict__ g, const float* __restrict__ bt,
    const float* __restrict__ og, const float* __restrict__ ob,
    unsigned short* __restrict__ znorm, int do_out)
{
    int row = blockIdx.x;
    const float* pa = xo + (size_t)row * D_;
    float* px = x + (size_t)row * D_;
    float v[3];
    float s = 0.f;
#pragma unroll
    for (int i = 0; i < 3; ++i) { int d = threadIdx.x + 256 * i; v[i] = pa[d] + px[d]; s += v[i]; }
    float mean = block_sum(s) * (1.f / (float)D_);
    float sq = 0.f;
#pragma unroll
    for (int i = 0; i < 3; ++i) { float t = v[i] - mean; sq += t * t; }
    float var = block_sum(sq) * (1.f / (float)D_);
    float inv = rsqrtf(var + EPS_);
    float o[3];
#pragma unroll
    for (int i = 0; i < 3; ++i) {
        int d = threadIdx.x + 256 * i;
        o[i] = (v[i] - mean) * inv * g[d] + bt[d];
        px[d] = o[i];
        xbf[(size_t)row * D_ + d] = bf16rn(o[i]);
    }
    int l = row % L_;
    if (do_out && l >= 2) {
        int b = row / L_;
        float s2 = o[0] + o[1] + o[2];
        float mean2 = block_sum(s2) * (1.f / (float)D_);
        float sq2 = 0.f;
#pragma unroll
        for (int i = 0; i < 3; ++i) { float t = o[i] - mean2; sq2 += t * t; }
        float var2 = block_sum(sq2) * (1.f / (float)D_);
        float inv2 = rsqrtf(var2 + EPS_);
#pragma unroll
        for (int i = 0; i < 3; ++i) {
            int d = threadIdx.x + 256 * i;
            znorm[((size_t)(b * 3 + (l - 2))) * D_ + d] = bf16rn((o[i] - mean2) * inv2 * og[d] + ob[d]);
        }
    }
}

extern "C" void kernel_launch(void* const* d_in, const int* in_sizes, int n_in,
                              void* d_out, int out_size, void* d_ws, size_t ws_size,
                              hipStream_t stream)
{
    const float* z_noisy  = (const float*)d_in[0];
    const float* text_emb = (const float*)d_in[1];
    const float* zin_b    = (const float*)d_in[3];
    const float* tin_b    = (const float*)d_in[5];
    const float* time_b   = (const float*)d_in[7];
    const float* part_emb = (const float*)d_in[8];
    const float* local_b  = (const float*)d_in[10];
    const float* f_b      = (const float*)d_in[12];
    const float* fuse_b   = (const float*)d_in[14];
    const float* final_b  = (const float*)d_in[16];
    const float* ln_g     = (const float*)d_in[17];
    const float* ln_b     = (const float*)d_in[18];
    const float* m_conv_w = (const float*)d_in[20];
    const float* m_conv_b = (const float*)d_in[21];
    const float* m_xproj_w= (const float*)d_in[22];
    const float* m_dt_w   = (const float*)d_in[23];
    const float* m_dt_b   = (const float*)d_in[24];
    const float* m_Alog   = (const float*)d_in[25];
    const float* m_Dp     = (const float*)d_in[26];
    const float* oln_g    = (const float*)d_in[28];
    const float* oln_b    = (const float*)d_in[29];
    const float* zout_b   = (const float*)d_in[31];
    const int*   timestep = (const int*)d_in[32];

    char* wsb = (char*)d_ws;
    unsigned short* wbf   = (unsigned short*)(wsb + OB_WBF);
    unsigned short* xpp   = (unsigned short*)(wsb + OB_XPP);
    unsigned short* tembb = (unsigned short*)(wsb + OB_TEMB);
    unsigned short* znormb= (unsigned short*)(wsb + OB_ZNORM);
    unsigned short* xbf   = (unsigned short*)(wsb + OB_XBF);
    unsigned short* tcbf  = (unsigned short*)(wsb + OB_TCBF);
    unsigned short* cat1b = (unsigned short*)(wsb + OB_CAT1);
    unsigned short* xtbf  = (unsigned short*)(wsb + OB_XTBF);
    unsigned short* xzbf  = (unsigned short*)(wsb + OB_XZBF);
    unsigned short* ucy   = (unsigned short*)(wsb + OB_UCY);
    unsigned short* cat2b = (unsigned short*)(wsb + OB_CAT2);
    float* x     = (float*)(wsb + OB_X);
    float* tc    = (float*)(wsb + OB_TC);
    float* zfeat = (float*)(wsb + OB_ZFEAT);
    unsigned short* tcf6 = (unsigned short*)(wsb + OB_ZFEAT);
    float* xo    = (float*)(wsb + OB_XO);
    float* part  = (float*)(wsb + OB_PART);

    unsigned short* local_bf = wbf + WO_LOCAL;
    unsigned short* f_bf     = wbf + WO_F;
    unsigned short* fuse_bf  = wbf + WO_FUSE;
    unsigned short* final_bf = wbf + WO_FINAL;
    unsigned short* in_bf    = wbf + WO_IN;
    unsigned short* out_bf   = wbf + WO_OUT;
    unsigned short* zin_bf   = wbf + WO_ZIN;
    unsigned short* tin_bf   = wbf + WO_TIN;
    unsigned short* time_bf  = wbf + WO_TIME;
    unsigned short* zout_bf  = wbf + WO_ZOUT;
    unsigned short* znz_bf   = wbf + WO_ZNOISY;
    unsigned short* text_bf  = wbf + WO_TEXT;

    auto ew = [&](int n) { return dim3((n + 255) / 256); };

    // ---------- prep: cvt + xpad + temb (one launch) ----------
    CvtArgs ca;
    ca.s[0] = (const float*)d_in[9];
    ca.s[1] = (const float*)d_in[11];
    ca.s[2] = (const float*)d_in[13];
    ca.s[3] = (const float*)d_in[15];
    ca.s[4] = (const float*)d_in[19];
    ca.s[5] = (const float*)d_in[27];
    ca.s[6] = (const float*)d_in[2];
    ca.s[7] = (const float*)d_in[4];
    ca.s[8] = (const float*)d_in[6];
    ca.s[9] = (const float*)d_in[30];
    ca.s[10] = z_noisy;
    ca.s[11] = text_emb;
    hipLaunchKernelGGL(prep_kernel, dim3(PREP_BLOCKS), dim3(256), 0, stream,
                       ca, wbf, m_xproj_w, xpp, timestep, tembb);

    // 512-thr parity-split 64x64 launcher (R24)
    auto g512 = [&](const unsigned short* A, int lda, const unsigned short* W, int wld,
                    const float* bias, const float* a0, const float* a1,
                    void* C, int ldc, int Mm, int Nn, int Kk, int epi, int ncap, int cd,
                    int gz, int zsplit, unsigned long long zA, unsigned long long zW,
                    unsigned long long zC) {
        dim3 g(Nn / 64, Mm / 64, gz);
        if (cd == 1)
            gemm512p_kernel<1, 8, 6><<<g, dim3(512), 0, stream>>>(
                A, lda, W, wld, bias, a0, a1, C, ldc, Mm, Nn, Kk, epi, ncap, zsplit, zA, zW, zC);
        else
            gemm512p_kernel<0, 8, 6><<<g, dim3(512), 0, stream>>>(
                A, lda, W, wld, bias, a0, a1, C, ldc, Mm, Nn, Kk, epi, ncap, zsplit, zA, zW, zC);
    };
    // shallow 64x64 launcher, 256 thr (grids > 256 blocks, co-residency: xproj)
    auto g64s = [&](const unsigned short* A, int lda, const unsigned short* W, int wld,
                    const float* bias, const float* a0, const float* a1,
                    void* C, int ldc, int Mm, int Nn, int Kk, int epi, int ncap, int cd,
                    int gz, int zsplit, unsigned long long zA, unsigned long long zW,
                    unsigned long long zC) {
        dim3 g(Nn / 64, Mm / 64, gz);
        if (cd == 1)
            gemm_bf16_kernel<64, 64, 1, 4, 2><<<g, dim3(256), 0, stream>>>(
                A, lda, W, wld, bias, a0, a1, C, ldc, Mm, Nn, Kk, epi, ncap, zsplit, zA, zW, zC);
        else
            gemm_bf16_kernel<64, 64, 0, 4, 2><<<g, dim3(256), 0, stream>>>(
                A, lda, W, wld, bias, a0, a1, C, ldc, Mm, Nn, Kk, epi, ncap, zsplit, zA, zW, zC);
    };

    // ---------- embedding ----------
    g512(tembb, D_, time_bf, D_, time_b, nullptr, nullptr, x, L_ * D_, B_, D_, D_, 0, D_, 1,
         1, 1, 0, 0, 0);
    g512(text_bf, TXT_, tin_bf, TXT_, tin_b, nullptr, nullptr, x + D_, L_ * D_, B_, D_, TXT_, 0, D_, 1,
         1, 1, 0, 0, 0);
    g512(znz_bf, LAT_, zin_bf, LAT_, zin_b, nullptr, nullptr, zfeat, D_, B_ * NP_, D_, LAT_, 0, D_, 1,
         1, 1, 0, 0, 0);
    hipLaunchKernelGGL(finalize_embed_kernel, ew(B_ * L_ * D_), dim3(256), 0, stream,
                       x, xbf, zfeat, part_emb, tc, tcbf);

    // batched tcf for ALL layers: [6][256][768] bf16 (z = layer)
    g512(tcbf, D_, f_bf + D_, 2 * D_, nullptr, nullptr, nullptr,
         tcf6, D_, B_, D_, D_, 0, D_, 0,
         6, 1, 0ull, (unsigned long long)D_ * 2 * D_, (unsigned long long)B_ * D_);

    // ---------- layers ----------
    for (int i = 0; i < NL_; ++i) {
        // xl = silu(x @ local^T + b) -> cat1 left
        g512(xbf, D_, local_bf + (size_t)i * D_ * D_, D_, local_b + (size_t)i * D_,
             nullptr, nullptr, cat1b, 2 * D_, M_, D_, D_, 1, D_, 0, 1, 1, 0, 0, 0);
        // f-gate: cat1 right = tc * sigm(xl@fw1 + f_b + tcf6[i])
        g512(cat1b, 2 * D_, f_bf + (size_t)i * D_ * 2 * D_, 2 * D_, f_b + (size_t)i * D_,
             (const float*)(tcf6 + (size_t)i * B_ * D_), tc,
             cat1b + D_, 2 * D_, M_, D_, D_, 3, D_, 0, 1, 1, 0, 0, 0);
        // fuse (K=1536)
        g512(cat1b, 2 * D_, fuse_bf + (size_t)i * D_ * 2 * D_, 2 * D_, fuse_b + (size_t)i * D_,
             nullptr, nullptr, xtbf, D_, M_, D_, 2 * D_, 0, D_, 0, 1, 1, 0, 0, 0);

        // in_proj: 1280 x 6144 -> 512-thr 128x128, grid (48,10) = 480, 16 waves/CU (R23)
        {
            dim3 g(6144 / 128, M_ / 128, 1);
            gemm512b_kernel<4, 2><<<g, dim3(512), 0, stream>>>(
                xtbf, D_, in_bf + (size_t)i * 4718592ull, D_, xzbf, 6144, D_);
        }
        hipLaunchKernelGGL(conv_silu_kernel, dim3(2 * M_ * DI_ / 8 / 256), dim3(256), 0, stream,
                           xzbf, m_conv_w + (size_t)i * 2 * DI_ * DC_,
                           m_conv_b + (size_t)i * 2 * DI_, ucy);
        // xproj split-K: grid (2,20,16) = 640 -> shallow 256-thr (R16 config)
        g64s(ucy, DI_, xpp + (size_t)i * 2 * 128 * DI_, DI_, nullptr, nullptr, nullptr,
             part, 80, M_, 128, 192, 0, 80, 1,
             16, 8, (unsigned long long)M_ * DI_, (unsigned long long)128 * DI_,
             (unsigned long long)M_ * 80);
        hipLaunchKernelGGL(dtscan_kernel, dim3(DI_ / 256, B_, 2), dim3(256), 0, stream,
                           part, ucy, xzbf,
                           m_dt_w + (size_t)i * 2 * DI_ * DTR_, m_dt_b + (size_t)i * 2 * DI_,
                           m_Alog + (size_t)i * 2 * DI_ * DS_, m_Dp + (size_t)i * 2 * DI_);
        // out: parity-split 64x64, grid (12,20,2) = 480, z = dir
        g512(ucy, DI_, out_bf + (size_t)i * 2 * D_ * DI_, DI_, nullptr, nullptr, nullptr,
             cat2b, 2 * D_, M_, D_, DI_, 0, D_, 0,
             2, 1, (unsigned long long)M_ * DI_, (unsigned long long)D_ * DI_, 768ull);
        // final (K=1536) -> xo f32
        g512(cat2b, 2 * D_, final_bf + (size_t)i * D_ * 2 * D_, 2 * D_, final_b + (size_t)i * D_,
             nullptr, nullptr, xo, D_, M_, D_, 2 * D_, 0, D_, 1, 1, 1, 0, 0, 0);
        // x = LN(xo + x); last layer also fuses the output LN -> znormb
        hipLaunchKernelGGL(ln_residual_kernel, dim3(M_), dim3(256), 0, stream,
                           xo, x, xbf, ln_g + (size_t)i * D_, ln_b + (size_t)i * D_,
                           oln_g, oln_b, znormb, (i == NL_ - 1) ? 1 : 0);
    }

    // ---------- output head (znormb filled by fused LN) ----------
    g512(znormb, D_, zout_bf, D_, zout_b, nullptr, nullptr,
         (float*)d_out, LAT_, B_ * NP_, LAT_, D_, 0, LAT_, 1, 1, 1, 0, 0, 0);
}

// Round 25
// 1056.370 us; speedup vs baseline: 1.0660x; 1.0660x over previous
//
#include <hip/hip_runtime.h>
#include <hip/hip_bf16.h>
#include <math.h>

// Problem constants
#define B_   256
#define NP_  3
#define LAT_ 512
#define TXT_ 768
#define D_   768
#define NL_  6
#define DI_  1536
#define DS_  16
#define DC_  4
#define DTR_ 48
#define L_   5
#define M_   (B_*L_)
#define EPS_ 1e-5f

// ---------------- workspace layout (BYTE offsets) ----------------
#define OB_WBF    0ull
#define OB_XPP    139591680ull
#define OB_TEMB   144310272ull
#define OB_ZNORM  144703488ull
#define OB_XBF    145883136ull
#define OB_TCBF   147849216ull
#define OB_CAT1   148242432ull
#define OB_XTBF   152174592ull
#define OB_XZBF   154140672ull
#define OB_UCY    169869312ull
#define OB_CAT2   177733632ull
#define OB_X      181665792ull
#define OB_TC     185597952ull
#define OB_ZFEAT  187170816ull   // zfeat f32 (dead after embed) -> tcf6 bf16 [6][256][768]
#define OB_XO     189530112ull
#define OB_PART   193462272ull

// bf16 weight arena element offsets
#define WO_LOCAL  0u
#define WO_F      3538944u
#define WO_FUSE   10616832u
#define WO_FINAL  17694720u
#define WO_IN     24772608u
#define WO_OUT    53084160u
#define WO_ZIN    67239936u
#define WO_TIN    67633152u
#define WO_TIME   68222976u
#define WO_ZOUT   68812800u
#define WO_ZNOISY 69206016u
#define WO_TEXT   69599232u
#define WO_END    69795840u
// NOTE: WO_END = 68160 waves * 1024 exactly -> no partial waves in cvt.

// prep kernel block partition
#define CVT_BLOCKS  17040u
#define XPAD_BLOCKS 1152u
#define TEMB_BLOCKS 384u
#define PREP_BLOCKS (CVT_BLOCKS + XPAD_BLOCKS + TEMB_BLOCKS)

typedef __attribute__((ext_vector_type(4))) float floatx4;
typedef __attribute__((ext_vector_type(8))) short short8;
typedef __attribute__((ext_vector_type(8))) unsigned short ushort8v;
typedef __attribute__((ext_vector_type(4))) unsigned short ushort4v;

__device__ __forceinline__ float sigm(float v) { return 1.f / (1.f + expf(-v)); }
__device__ __forceinline__ float softplus(float v) {
    return fmaxf(v, 0.f) + log1pf(expf(-fabsf(v)));
}
__device__ __forceinline__ unsigned short bf16rn(float f) {
    unsigned int u = __builtin_bit_cast(unsigned int, f);
    u = (u + 0x7fffu + ((u >> 16) & 1u)) >> 16;
    return (unsigned short)u;
}
__device__ __forceinline__ float b2f(unsigned short u) {
    unsigned int x = ((unsigned int)u) << 16;
    return __builtin_bit_cast(float, x);
}

template<int N> __device__ __forceinline__ void waitv() {
    asm volatile("s_waitcnt vmcnt(%0)" :: "i"(N) : "memory");
}

// ---------------- prep: cvt (batched NT loads) + xpad + temb in ONE launch ----------
struct CvtArgs { const float* s[12]; };

__global__ __launch_bounds__(256) void prep_kernel(
    CvtArgs a, unsigned short* __restrict__ dst,
    const float* __restrict__ xw, unsigned short* __restrict__ xpd,
    const int* __restrict__ ts, unsigned short* __restrict__ temb)
{
    unsigned bid = blockIdx.x;
    if (bid < CVT_BLOCKS) {
        constexpr unsigned ends[12] = {
            3538944u, 10616832u, 17694720u, 24772608u, 53084160u, 67239936u,
            67633152u, 68222976u, 68812800u, 69206016u, 69599232u, 69795840u };
        const unsigned wv = (bid * 256u + threadIdx.x) >> 6;
        const unsigned lane = threadIdx.x & 63u;
        const unsigned wbase = wv * 1024u;
        unsigned idxq[4];
        floatx4 v[4];
#pragma unroll
        for (int q = 0; q < 4; ++q) {
            unsigned gbase = wbase + (unsigned)q * 256u;
            int t = 0;
            while (gbase >= ends[t]) ++t;
            unsigned start = t ? ends[t - 1] : 0u;
            idxq[q] = gbase + lane * 4u;
            v[q] = __builtin_nontemporal_load((const floatx4*)(a.s[t] + (idxq[q] - start)));
        }
#pragma unroll
        for (int q = 0; q < 4; ++q) {
            ushort4v o = { bf16rn(v[q][0]), bf16rn(v[q][1]), bf16rn(v[q][2]), bf16rn(v[q][3]) };
            __builtin_nontemporal_store(o, (ushort4v*)(dst + idxq[q]));
        }
    } else if (bid < CVT_BLOCKS + XPAD_BLOCKS) {
        unsigned i8 = ((bid - CVT_BLOCKS) * 256u + threadIdx.x) * 8u;
        if (i8 >= 12u * 128u * 1536u) return;
        unsigned pi = i8 / (128u * 1536u);
        unsigned rem = i8 - pi * 128u * 1536u;
        unsigned row = rem / 1536u, col = rem - row * 1536u;
        ushort8v o = {0, 0, 0, 0, 0, 0, 0, 0};
        if (row < 80u) {
            const float* s = xw + ((size_t)pi * 80u + row) * 1536u + col;
            floatx4 v0 = __builtin_nontemporal_load((const floatx4*)s);
            floatx4 v1 = __builtin_nontemporal_load((const floatx4*)(s + 4));
            o = ushort8v{ bf16rn(v0[0]), bf16rn(v0[1]), bf16rn(v0[2]), bf16rn(v0[3]),
                          bf16rn(v1[0]), bf16rn(v1[1]), bf16rn(v1[2]), bf16rn(v1[3]) };
        }
        *(ushort8v*)(xpd + i8) = o;
    } else {
        int idx = (bid - CVT_BLOCKS - XPAD_BLOCKS) * 256 + threadIdx.x;
        if (idx >= B_ * 384) return;
        int j = idx % 384, b = idx / 384;
        float f = expf(-logf(10000.f) * (float)j / 384.f);
        float targ = (float)ts[b] * f;
        temb[(size_t)b * D_ + j]       = bf16rn(cosf(targ));
        temb[(size_t)b * D_ + 384 + j] = bf16rn(sinf(targ));
    }
}

// ============ bf16 MFMA GEMM (256 thr), DEPTH pipeline, counted vmcnt ============
// 64x64 DEPTH=4/PF=2: xproj (>256-block grid, co-residency).
template<int BM, int BN, int CD, int DEPTH, int PF>
__global__ __launch_bounds__(256) void gemm_bf16_kernel(
    const unsigned short* __restrict__ A, int lda,
    const unsigned short* __restrict__ W, int wld,
    const float* __restrict__ bias,
    const float* __restrict__ aux0,
    const float* __restrict__ aux1,
    void* __restrict__ Cv, int ldc,
    int M, int N, int K, int epi, int ncap,
    int zsplit, unsigned long long zA, unsigned long long zW, unsigned long long zC)
{
    constexpr int GA = BM / 64;
    constexpr int GB = BN / 64;
    constexpr int LPS = GA + GB;
    constexpr int FRM = BM / 32;
    constexpr int FRN = BN / 32;
    constexpr int BMSK = DEPTH - 1;

    const int z = blockIdx.z;
    const int dirz = z / zsplit, ksz = z - dirz * zsplit;
    A += (unsigned long long)dirz * zA + (unsigned long long)ksz * (unsigned)K;
    W += (unsigned long long)dirz * zW + (unsigned long long)ksz * (unsigned)K;

    __shared__ unsigned short lds[DEPTH][(BM + BN) * 32];

    const int tid = threadIdx.x;
    const int m0 = blockIdx.y * BM, n0 = blockIdx.x * BN;
    const int w = tid >> 6, lane = tid & 63;
    const int wr = w >> 1, wc = w & 1;
    const int lrow = lane & 15;
    const int lk = (lane >> 4) << 3;

    const int rA = tid >> 2, sA = tid & 3;
    const int scA = ((sA ^ ((rA >> 1) & 3)) << 3);
    floatx4 acc[FRM][FRN] = {};

    auto stage = [&](int buf, int k0) {
        unsigned short* base = &lds[buf][0];
#pragma unroll
        for (int i = 0; i < GA; ++i) {
            int t = tid + i * 256;
            int r = t >> 2;
            const unsigned short* src = A + (size_t)(m0 + r) * lda + k0 + scA;
            __builtin_amdgcn_global_load_lds(
                (const __attribute__((address_space(1))) unsigned int*)(const void*)src,
                (__attribute__((address_space(3))) unsigned int*)(void*)(base + i * 2048 + w * 512),
                16, 0, 0);
        }
#pragma unroll
        for (int i = 0; i < GB; ++i) {
            int t = tid + i * 256;
            int r = t >> 2;
            const unsigned short* src = W + (size_t)(n0 + r) * wld + k0 + scA;
            __builtin_amdgcn_global_load_lds(
                (const __attribute__((address_space(1))) unsigned int*)(const void*)src,
                (__attribute__((address_space(3))) unsigned int*)(void*)(base + BM * 32 + i * 2048 + w * 512),
                16, 0, 0);
        }
    };

    const int nt = K >> 5;
#pragma unroll
    for (int s = 0; s < PF; ++s)
        if (s < nt) stage(s, s << 5);

    int offA[FRM], offB[FRN];
#pragma unroll
    for (int i = 0; i < FRM; ++i) {
        int row = wr * (BM / 2) + i * 16 + lrow;
        offA[i] = row * 32 + (lk ^ (((row >> 1) & 3) << 3));
    }
#pragma unroll
    for (int j = 0; j < FRN; ++j) {
        int row = wc * (BN / 2) + j * 16 + lrow;
        offB[j] = BM * 32 + row * 32 + (lk ^ (((row >> 1) & 3) << 3));
    }

    for (int t = 0; t < nt; ++t) {
        int rem = nt - 1 - t;
        if (rem >= PF) { stage((t + PF) & BMSK, (t + PF) << 5); waitv<PF * LPS>(); }
        else if (rem == 5) waitv<5 * LPS>();
        else if (rem == 4) waitv<4 * LPS>();
        else if (rem == 3) waitv<3 * LPS>();
        else if (rem == 2) waitv<2 * LPS>();
        else if (rem == 1) waitv<1 * LPS>();
        else               waitv<0>();
        __builtin_amdgcn_s_barrier();
        const unsigned short* pl = &lds[t & BMSK][0];
        short8 af[FRM], bfv[FRN];
#pragma unroll
        for (int i = 0; i < FRM; ++i) af[i] = *(const short8*)(pl + offA[i]);
#pragma unroll
        for (int j = 0; j < FRN; ++j) bfv[j] = *(const short8*)(pl + offB[j]);
#pragma unroll
        for (int i = 0; i < FRM; ++i)
#pragma unroll
            for (int j = 0; j < FRN; ++j)
                acc[i][j] = __builtin_amdgcn_mfma_f32_16x16x32_bf16(af[i], bfv[j], acc[i][j], 0, 0, 0);
    }

#pragma unroll
    for (int i = 0; i < FRM; ++i) {
        int row0 = m0 + wr * (BM / 2) + i * 16 + (lane >> 4) * 4;
#pragma unroll
        for (int j = 0; j < FRN; ++j) {
            int col = n0 + wc * (BN / 2) + j * 16 + lrow;
            if (col >= ncap) continue;
            float bb = bias ? bias[col] : 0.f;
#pragma unroll
            for (int r = 0; r < 4; ++r) {
                int row = row0 + r;
                float v = acc[i][j][r] + bb;
                if (epi == 1) {
                    v = v * sigm(v);
                } else if (epi == 3) {
                    int b = row / 5;
                    v = acc[i][j][r] + bb + b2f(((const unsigned short*)aux0)[(size_t)b * 768 + col]);
                    v = aux1[(size_t)b * 768 + col] * sigm(v);
                }
                size_t off = (size_t)z * zC + (size_t)row * ldc + col;
                if (CD == 1) ((float*)Cv)[off] = v;
                else         ((unsigned short*)Cv)[off] = bf16rn(v);
            }
        }
    }
}

// ============ 512-thread 64x64 deep GEMM: 8 waves/CU (R21/R22 proven; R24's parity
// split regressed — barrier-synced iteration-splitting idles waves, reverted) ============
template<int CD, int DEPTH, int PF>
__global__ __launch_bounds__(512) void gemm512_kernel(
    const unsigned short* __restrict__ A, int lda,
    const unsigned short* __restrict__ W, int wld,
    const float* __restrict__ bias,
    const float* __restrict__ aux0,
    const float* __restrict__ aux1,
    void* __restrict__ Cv, int ldc,
    int M, int N, int K, int epi, int ncap,
    int zsplit, unsigned long long zA, unsigned long long zW, unsigned long long zC)
{
    constexpr int BMSK = DEPTH - 1;
    const int z = blockIdx.z;
    const int dirz = z / zsplit, ksz = z - dirz * zsplit;
    A += (unsigned long long)dirz * zA + (unsigned long long)ksz * (unsigned)K;
    W += (unsigned long long)dirz * zW + (unsigned long long)ksz * (unsigned)K;

    __shared__ unsigned short lds[DEPTH][128 * 32];

    const int tid = threadIdx.x;
    const int m0 = blockIdx.y * 64, n0 = blockIdx.x * 64;
    const int w = tid >> 6, lane = tid & 63;
    const int wr = w >> 1, wc = w & 1;          // 4 x 2 wave grid; wave-tile 16x32
    const int lrow = lane & 15;
    const int lk = (lane >> 4) << 3;

    const int st = tid & 255;
    const int rA = st >> 2, sA = st & 3;
    const int scA = ((sA ^ ((rA >> 1) & 3)) << 3);
    const bool isA = (tid < 256);
    floatx4 acc[2] = {};

    auto stage = [&](int buf, int k0) {
        unsigned short* dstp = &lds[buf][0] + (isA ? w * 512 : 2048 + (w - 4) * 512);
        const unsigned short* src = isA
            ? A + (size_t)(m0 + rA) * lda + k0 + scA
            : W + (size_t)(n0 + rA) * wld + k0 + scA;
        __builtin_amdgcn_global_load_lds(
            (const __attribute__((address_space(1))) unsigned int*)(const void*)src,
            (__attribute__((address_space(3))) unsigned int*)(void*)dstp,
            16, 0, 0);
    };

    const int nt = K >> 5;
#pragma unroll
    for (int s = 0; s < PF; ++s)
        if (s < nt) stage(s, s << 5);

    const int rowA = wr * 16 + lrow;
    const int offA = rowA * 32 + (lk ^ (((rowA >> 1) & 3) << 3));
    int offB[2];
#pragma unroll
    for (int j = 0; j < 2; ++j) {
        int rowB = wc * 32 + j * 16 + lrow;
        offB[j] = 2048 + rowB * 32 + (lk ^ (((rowB >> 1) & 3) << 3));
    }

    for (int t = 0; t < nt; ++t) {
        int rem = nt - 1 - t;
        if (rem >= PF) { stage((t + PF) & BMSK, (t + PF) << 5); waitv<PF>(); }
        else if (rem == 5) waitv<5>();
        else if (rem == 4) waitv<4>();
        else if (rem == 3) waitv<3>();
        else if (rem == 2) waitv<2>();
        else if (rem == 1) waitv<1>();
        else               waitv<0>();
        __builtin_amdgcn_s_barrier();
        const unsigned short* pl = &lds[t & BMSK][0];
        short8 af = *(const short8*)(pl + offA);
        short8 b0 = *(const short8*)(pl + offB[0]);
        short8 b1 = *(const short8*)(pl + offB[1]);
        acc[0] = __builtin_amdgcn_mfma_f32_16x16x32_bf16(af, b0, acc[0], 0, 0, 0);
        acc[1] = __builtin_amdgcn_mfma_f32_16x16x32_bf16(af, b1, acc[1], 0, 0, 0);
    }

    int row0 = m0 + wr * 16 + (lane >> 4) * 4;
#pragma unroll
    for (int j = 0; j < 2; ++j) {
        int col = n0 + wc * 32 + j * 16 + lrow;
        if (col >= ncap) continue;
        float bb = bias ? bias[col] : 0.f;
#pragma unroll
        for (int r = 0; r < 4; ++r) {
            int row = row0 + r;
            float v = acc[j][r] + bb;
            if (epi == 1) {
                v = v * sigm(v);
            } else if (epi == 3) {
                int b = row / 5;
                v = acc[j][r] + bb + b2f(((const unsigned short*)aux0)[(size_t)b * 768 + col]);
                v = aux1[(size_t)b * 768 + col] * sigm(v);
            }
            size_t off = (size_t)z * zC + (size_t)row * ldc + col;
            if (CD == 1) ((float*)Cv)[off] = v;
            else         ((unsigned short*)Cv)[off] = bf16rn(v);
        }
    }
}

// ============ 512-thread 128x128 GEMM (R23, in_proj): 8 waves/block, 16 waves/CU ======
template<int DEPTH, int PF>
__global__ __launch_bounds__(512) void gemm512b_kernel(
    const unsigned short* __restrict__ A, int lda,
    const unsigned short* __restrict__ W, int wld,
    unsigned short* __restrict__ C, int ldc, int K)
{
    constexpr int BMSK = DEPTH - 1;
    __shared__ unsigned short lds[DEPTH][8192];

    const int tid = threadIdx.x;
    const int m0 = blockIdx.y * 128, n0 = blockIdx.x * 128;
    const int w = tid >> 6, lane = tid & 63;
    const int wr = w >> 2, wc = w & 3;          // 2 x 4 waves; wave-tile 64x32
    const int lrow = lane & 15;
    const int lk = (lane >> 4) << 3;

    const int rA = tid >> 2, sA = tid & 3;      // 128 rows x 4 slots
    const int scA = ((sA ^ ((rA >> 1) & 3)) << 3);
    floatx4 acc[4][2] = {};

    auto stage = [&](int buf, int k0) {
        unsigned short* base = &lds[buf][0];
        const unsigned short* srcA = A + (size_t)(m0 + rA) * lda + k0 + scA;
        __builtin_amdgcn_global_load_lds(
            (const __attribute__((address_space(1))) unsigned int*)(const void*)srcA,
            (__attribute__((address_space(3))) unsigned int*)(void*)(base + w * 512),
            16, 0, 0);
        const unsigned short* srcB = W + (size_t)(n0 + rA) * wld + k0 + scA;
        __builtin_amdgcn_global_load_lds(
            (const __attribute__((address_space(1))) unsigned int*)(const void*)srcB,
            (__attribute__((address_space(3))) unsigned int*)(void*)(base + 4096 + w * 512),
            16, 0, 0);
    };

    const int nt = K >> 5;
#pragma unroll
    for (int s = 0; s < PF; ++s)
        if (s < nt) stage(s, s << 5);

    int offA[4], offB[2];
#pragma unroll
    for (int i = 0; i < 4; ++i) {
        int row = wr * 64 + i * 16 + lrow;
        offA[i] = row * 32 + (lk ^ (((row >> 1) & 3) << 3));
    }
#pragma unroll
    for (int j = 0; j < 2; ++j) {
        int row = wc * 32 + j * 16 + lrow;
        offB[j] = 4096 + row * 32 + (lk ^ (((row >> 1) & 3) << 3));
    }

    for (int t = 0; t < nt; ++t) {
        int rem = nt - 1 - t;
        if (rem >= PF) { stage((t + PF) & BMSK, (t + PF) << 5); waitv<PF * 2>(); }
        else if (rem == 1) waitv<2>();
        else               waitv<0>();
        __builtin_amdgcn_s_barrier();
        const unsigned short* pl = &lds[t & BMSK][0];
        short8 af[4], bfv[2];
#pragma unroll
        for (int i = 0; i < 4; ++i) af[i] = *(const short8*)(pl + offA[i]);
#pragma unroll
        for (int j = 0; j < 2; ++j) bfv[j] = *(const short8*)(pl + offB[j]);
#pragma unroll
        for (int i = 0; i < 4; ++i)
#pragma unroll
            for (int j = 0; j < 2; ++j)
                acc[i][j] = __builtin_amdgcn_mfma_f32_16x16x32_bf16(af[i], bfv[j], acc[i][j], 0, 0, 0);
    }

#pragma unroll
    for (int i = 0; i < 4; ++i) {
        int row0 = m0 + wr * 64 + i * 16 + (lane >> 4) * 4;
#pragma unroll
        for (int j = 0; j < 2; ++j) {
            int col = n0 + wc * 32 + j * 16 + lrow;
#pragma unroll
            for (int r = 0; r < 4; ++r)
                C[(size_t)(row0 + r) * ldc + col] = bf16rn(acc[i][j][r]);
        }
    }
}

// ---------------- scatter z_feat + part_emb, add PE, write x/x_bf/tc/tc_bf -------
__global__ void finalize_embed_kernel(float* __restrict__ x,
                                      unsigned short* __restrict__ xbf,
                                      const float* __restrict__ zfeat,
                                      const float* __restrict__ part_emb,
                                      float* __restrict__ tc,
                                      unsigned short* __restrict__ tcbf)
{
    int idx = blockIdx.x * blockDim.x + threadIdx.x;
    if (idx >= B_ * L_ * D_) return;
    int d = idx % D_;
    int bl = idx / D_;
    int l = bl % L_, b = bl / L_;
    float v;
    if (l >= 2) v = zfeat[((size_t)(b * 3 + (l - 2))) * D_ + d] + part_emb[(size_t)(l - 2) * D_ + d];
    else        v = x[idx];
    int j = d >> 1;
    float dv = expf((float)(2 * j) * (-logf(10000.f) / (float)D_));
    float ang = (float)l * dv;
    v += (d & 1) ? cosf(ang) : sinf(ang);
    x[idx] = v;
    xbf[idx] = bf16rn(v);
    if (l == 1) { tc[(size_t)b * D_ + d] = v; tcbf[(size_t)b * D_ + d] = bf16rn(v); }
}

// ---------------- vectorized conv (8 ch/thread) + SiLU -> ucy bf16 ----------------
__global__ __launch_bounds__(256) void conv_silu_kernel(
    const unsigned short* __restrict__ xz,
    const float* __restrict__ cw,
    const float* __restrict__ cb,
    unsigned short* __restrict__ ucy)
{
    int idx = blockIdx.x * 256 + threadIdx.x;          // over 2*M*DI/8
    if (idx >= 2 * M_ * DI_ / 8) return;
    int c8 = (idx % (DI_ / 8)) * 8;
    int t2 = idx / (DI_ / 8);
    int bl = t2 % M_, dir = t2 / M_;
    int l = bl % L_, b = bl / L_;

    float acc[8];
    const float* cbp = cb + dir * DI_ + c8;
#pragma unroll
    for (int e = 0; e < 8; ++e) acc[e] = cbp[e];
    floatx4 w[8];
#pragma unroll
    for (int e = 0; e < 8; ++e)
        w[e] = *(const floatx4*)(cw + ((size_t)(dir * DI_ + c8 + e)) * DC_);
#pragma unroll
    for (int k = 0; k < DC_; ++k) {
        int lp = dir ? (l + 3 - k) : (l + k - 3);
        if (lp >= 0 && lp < L_) {
            ushort8v xv = *(const ushort8v*)(xz + ((size_t)(b * L_ + lp)) * 6144 + dir * 3072 + c8);
#pragma unroll
            for (int e = 0; e < 8; ++e) acc[e] = fmaf(w[e][k], b2f(xv[e]), acc[e]);
        }
    }
    ushort8v o;
#pragma unroll
    for (int e = 0; e < 8; ++e) { float v = acc[e]; o[e] = bf16rn(v * sigm(v)); }
    *(ushort8v*)(ucy + (size_t)idx * 8) = o;
}

// ---------------- fused: split-K reduce + dt-proj + softplus + scan + gate ----------
__global__ __launch_bounds__(256) void dtscan_kernel(
    const float* __restrict__ part,
    unsigned short* ucy,
    const unsigned short* __restrict__ xz,
    const float* __restrict__ dt_w,
    const float* __restrict__ dt_b,
    const float* __restrict__ Alog,
    const float* __restrict__ Dp)
{
    __shared__ float xd[L_][80];
    const int dir = blockIdx.z;
    const int b = blockIdx.y;
    const int ch = blockIdx.x * 256 + threadIdx.x;

    for (int o = threadIdx.x; o < L_ * 80; o += 256) {
        int l = o / 80, n = o - l * 80;
        float s = 0.f;
#pragma unroll
        for (int ks = 0; ks < 8; ++ks)
            s += part[((size_t)(dir * 8 + ks) * M_ + b * L_ + l) * 80 + n];
        xd[l][n] = s;
    }
    __syncthreads();

    const int cg = dir * DI_ + ch;
    float dt[L_];
    const float* wp = dt_w + (size_t)cg * DTR_;
    float dbv = dt_b[cg];
#pragma unroll
    for (int l = 0; l < L_; ++l) {
        float v = dbv;
#pragma unroll
        for (int r = 0; r < DTR_; ++r) v = fmaf(xd[l][r], wp[r], v);
        dt[l] = softplus(v);
    }

    float Aa[DS_], h[DS_];
#pragma unroll
    for (int s = 0; s < DS_; ++s) { Aa[s] = -expf(Alog[(size_t)cg * DS_ + s]); h[s] = 0.f; }
    float Dv = Dp[cg];

#pragma unroll
    for (int t = 0; t < L_; ++t) {
        const int l = dir ? (L_ - 1 - t) : t;
        size_t base = (size_t)(b * L_ + l);
        size_t uoff = ((size_t)dir * M_ + base) * DI_ + ch;
        float dtv = dt[l];
        float ucv = b2f(ucy[uoff]);
        float du = dtv * ucv;
        float y = 0.f;
#pragma unroll
        for (int s = 0; s < DS_; ++s) {
            h[s] = h[s] * expf(dtv * Aa[s]) + du * xd[l][48 + s];
            y = fmaf(h[s], xd[l][64 + s], y);
        }
        float zv = b2f(xz[base * 6144 + dir * 3072 + 1536 + ch]);
        ucy[uoff] = bf16rn((y + Dv * ucv) * (zv * sigm(zv)));
    }
}

// ---------------- block reduce helper ----------------
__device__ __forceinline__ float block_sum(float v)
{
    __shared__ float sd[4];
#pragma unroll
    for (int o = 1; o < 64; o <<= 1) v += __shfl_xor(v, o, 64);
    int lane = threadIdx.x & 63, wid = threadIdx.x >> 6;
    if (lane == 0) sd[wid] = v;
    __syncthreads();
    v = sd[0] + sd[1] + sd[2] + sd[3];
    __syncthreads();
    return v;
}

// LN(xo + x) -> x, xbf. If do_out and row%5>=2: second LN with oln params -> znorm.
__global__ __launch_bounds__(256) void ln_residual_kernel(
    const float* __restrict__ xo, float* __restrict__ x,
    unsigned short* __restrict__ xbf,
    const float* __restrict__ g, const float* __restrict__ bt,
    const float* __restrict__ og, const float* __restrict__ ob,
    unsigned short* __restrict__ znorm, int do_out)
{
    int row = blockIdx.x;
    const float* pa = xo + (size_t)row * D_;
    float* px = x + (size_t)row * D_;
    float v[3];
    float s = 0.f;
#pragma unroll
    for (int i = 0; i < 3; ++i) { int d = threadIdx.x + 256 * i; v[i] = pa[d] + px[d]; s += v[i]; }
    float mean = block_sum(s) * (1.f / (float)D_);
    float sq = 0.f;
#pragma unroll
    for (int i = 0; i < 3; ++i) { float t = v[i] - mean; sq += t * t; }
    float var = block_sum(sq) * (1.f / (float)D_);
    float inv = rsqrtf(var + EPS_);
    float o[3];
#pragma unroll
    for (int i = 0; i < 3; ++i) {
        int d = threadIdx.x + 256 * i;
        o[i] = (v[i] - mean) * inv * g[d] + bt[d];
        px[d] = o[i];
        xbf[(size_t)row * D_ + d] = bf16rn(o[i]);
    }
    int l = row % L_;
    if (do_out && l >= 2) {
        int b = row / L_;
        float s2 = o[0] + o[1] + o[2];
        float mean2 = block_sum(s2) * (1.f / (float)D_);
        float sq2 = 0.f;
#pragma unroll
        for (int i = 0; i < 3; ++i) { float t = o[i] - mean2; sq2 += t * t; }
        float var2 = block_sum(sq2) * (1.f / (float)D_);
        float inv2 = rsqrtf(var2 + EPS_);
#pragma unroll
        for (int i = 0; i < 3; ++i) {
            int d = threadIdx.x + 256 * i;
            znorm[((size_t)(b * 3 + (l - 2))) * D_ + d] = bf16rn((o[i] - mean2) * inv2 * og[d] + ob[d]);
        }
    }
}

extern "C" void kernel_launch(void* const* d_in, const int* in_sizes, int n_in,
                              void* d_out, int out_size, void* d_ws, size_t ws_size,
                              hipStream_t stream)
{
    const float* z_noisy  = (const float*)d_in[0];
    const float* text_emb = (const float*)d_in[1];
    const float* zin_b    = (const float*)d_in[3];
    const float* tin_b    = (const float*)d_in[5];
    const float* time_b   = (const float*)d_in[7];
    const float* part_emb = (const float*)d_in[8];
    const float* local_b  = (const float*)d_in[10];
    const float* f_b      = (const float*)d_in[12];
    const float* fuse_b   = (const float*)d_in[14];
    const float* final_b  = (const float*)d_in[16];
    const float* ln_g     = (const float*)d_in[17];
    const float* ln_b     = (const float*)d_in[18];
    const float* m_conv_w = (const float*)d_in[20];
    const float* m_conv_b = (const float*)d_in[21];
    const float* m_xproj_w= (const float*)d_in[22];
    const float* m_dt_w   = (const float*)d_in[23];
    const float* m_dt_b   = (const float*)d_in[24];
    const float* m_Alog   = (const float*)d_in[25];
    const float* m_Dp     = (const float*)d_in[26];
    const float* oln_g    = (const float*)d_in[28];
    const float* oln_b    = (const float*)d_in[29];
    const float* zout_b   = (const float*)d_in[31];
    const int*   timestep = (const int*)d_in[32];

    char* wsb = (char*)d_ws;
    unsigned short* wbf   = (unsigned short*)(wsb + OB_WBF);
    unsigned short* xpp   = (unsigned short*)(wsb + OB_XPP);
    unsigned short* tembb = (unsigned short*)(wsb + OB_TEMB);
    unsigned short* znormb= (unsigned short*)(wsb + OB_ZNORM);
    unsigned short* xbf   = (unsigned short*)(wsb + OB_XBF);
    unsigned short* tcbf  = (unsigned short*)(wsb + OB_TCBF);
    unsigned short* cat1b = (unsigned short*)(wsb + OB_CAT1);
    unsigned short* xtbf  = (unsigned short*)(wsb + OB_XTBF);
    unsigned short* xzbf  = (unsigned short*)(wsb + OB_XZBF);
    unsigned short* ucy   = (unsigned short*)(wsb + OB_UCY);
    unsigned short* cat2b = (unsigned short*)(wsb + OB_CAT2);
    float* x     = (float*)(wsb + OB_X);
    float* tc    = (float*)(wsb + OB_TC);
    float* zfeat = (float*)(wsb + OB_ZFEAT);
    unsigned short* tcf6 = (unsigned short*)(wsb + OB_ZFEAT);
    float* xo    = (float*)(wsb + OB_XO);
    float* part  = (float*)(wsb + OB_PART);

    unsigned short* local_bf = wbf + WO_LOCAL;
    unsigned short* f_bf     = wbf + WO_F;
    unsigned short* fuse_bf  = wbf + WO_FUSE;
    unsigned short* final_bf = wbf + WO_FINAL;
    unsigned short* in_bf    = wbf + WO_IN;
    unsigned short* out_bf   = wbf + WO_OUT;
    unsigned short* zin_bf   = wbf + WO_ZIN;
    unsigned short* tin_bf   = wbf + WO_TIN;
    unsigned short* time_bf  = wbf + WO_TIME;
    unsigned short* zout_bf  = wbf + WO_ZOUT;
    unsigned short* znz_bf   = wbf + WO_ZNOISY;
    unsigned short* text_bf  = wbf + WO_TEXT;

    auto ew = [&](int n) { return dim3((n + 255) / 256); };

    // ---------- prep: cvt + xpad + temb (one launch) ----------
    CvtArgs ca;
    ca.s[0] = (const float*)d_in[9];
    ca.s[1] = (const float*)d_in[11];
    ca.s[2] = (const float*)d_in[13];
    ca.s[3] = (const float*)d_in[15];
    ca.s[4] = (const float*)d_in[19];
    ca.s[5] = (const float*)d_in[27];
    ca.s[6] = (const float*)d_in[2];
    ca.s[7] = (const float*)d_in[4];
    ca.s[8] = (const float*)d_in[6];
    ca.s[9] = (const float*)d_in[30];
    ca.s[10] = z_noisy;
    ca.s[11] = text_emb;
    hipLaunchKernelGGL(prep_kernel, dim3(PREP_BLOCKS), dim3(256), 0, stream,
                       ca, wbf, m_xproj_w, xpp, timestep, tembb);

    // 512-thr deep 64x64 launcher (8 waves/CU; all <=~512-block grids)
    auto g512 = [&](const unsigned short* A, int lda, const unsigned short* W, int wld,
                    const float* bias, const float* a0, const float* a1,
                    void* C, int ldc, int Mm, int Nn, int Kk, int epi, int ncap, int cd,
                    int gz, int zsplit, unsigned long long zA, unsigned long long zW,
                    unsigned long long zC) {
        dim3 g(Nn / 64, Mm / 64, gz);
        if (cd == 1)
            gemm512_kernel<1, 8, 6><<<g, dim3(512), 0, stream>>>(
                A, lda, W, wld, bias, a0, a1, C, ldc, Mm, Nn, Kk, epi, ncap, zsplit, zA, zW, zC);
        else
            gemm512_kernel<0, 8, 6><<<g, dim3(512), 0, stream>>>(
                A, lda, W, wld, bias, a0, a1, C, ldc, Mm, Nn, Kk, epi, ncap, zsplit, zA, zW, zC);
    };
    // shallow 64x64 launcher, 256 thr (grids > 256 blocks, co-residency: xproj)
    auto g64s = [&](const unsigned short* A, int lda, const unsigned short* W, int wld,
                    const float* bias, const float* a0, const float* a1,
                    void* C, int ldc, int Mm, int Nn, int Kk, int epi, int ncap, int cd,
                    int gz, int zsplit, unsigned long long zA, unsigned long long zW,
                    unsigned long long zC) {
        dim3 g(Nn / 64, Mm / 64, gz);
        if (cd == 1)
            gemm_bf16_kernel<64, 64, 1, 4, 2><<<g, dim3(256), 0, stream>>>(
                A, lda, W, wld, bias, a0, a1, C, ldc, Mm, Nn, Kk, epi, ncap, zsplit, zA, zW, zC);
        else
            gemm_bf16_kernel<64, 64, 0, 4, 2><<<g, dim3(256), 0, stream>>>(
                A, lda, W, wld, bias, a0, a1, C, ldc, Mm, Nn, Kk, epi, ncap, zsplit, zA, zW, zC);
    };

    // ---------- embedding (512-thr deep) ----------
    g512(tembb, D_, time_bf, D_, time_b, nullptr, nullptr, x, L_ * D_, B_, D_, D_, 0, D_, 1,
         1, 1, 0, 0, 0);
    g512(text_bf, TXT_, tin_bf, TXT_, tin_b, nullptr, nullptr, x + D_, L_ * D_, B_, D_, TXT_, 0, D_, 1,
         1, 1, 0, 0, 0);
    g512(znz_bf, LAT_, zin_bf, LAT_, zin_b, nullptr, nullptr, zfeat, D_, B_ * NP_, D_, LAT_, 0, D_, 1,
         1, 1, 0, 0, 0);
    hipLaunchKernelGGL(finalize_embed_kernel, ew(B_ * L_ * D_), dim3(256), 0, stream,
                       x, xbf, zfeat, part_emb, tc, tcbf);

    // batched tcf for ALL layers: [6][256][768] bf16 (z = layer)
    g512(tcbf, D_, f_bf + D_, 2 * D_, nullptr, nullptr, nullptr,
         tcf6, D_, B_, D_, D_, 0, D_, 0,
         6, 1, 0ull, (unsigned long long)D_ * 2 * D_, (unsigned long long)B_ * D_);

    // ---------- layers ----------
    for (int i = 0; i < NL_; ++i) {
        // xl = silu(x @ local^T + b) -> cat1 left (512-thr deep)
        g512(xbf, D_, local_bf + (size_t)i * D_ * D_, D_, local_b + (size_t)i * D_,
             nullptr, nullptr, cat1b, 2 * D_, M_, D_, D_, 1, D_, 0, 1, 1, 0, 0, 0);
        // f-gate: cat1 right = tc * sigm(xl@fw1 + f_b + tcf6[i])
        g512(cat1b, 2 * D_, f_bf + (size_t)i * D_ * 2 * D_, 2 * D_, f_b + (size_t)i * D_,
             (const float*)(tcf6 + (size_t)i * B_ * D_), tc,
             cat1b + D_, 2 * D_, M_, D_, D_, 3, D_, 0, 1, 1, 0, 0, 0);
        // fuse (K=1536)
        g512(cat1b, 2 * D_, fuse_bf + (size_t)i * D_ * 2 * D_, 2 * D_, fuse_b + (size_t)i * D_,
             nullptr, nullptr, xtbf, D_, M_, D_, 2 * D_, 0, D_, 0, 1, 1, 0, 0, 0);

        // in_proj: 1280 x 6144 -> 512-thr 128x128, grid (48,10) = 480, 16 waves/CU (R23)
        {
            dim3 g(6144 / 128, M_ / 128, 1);
            gemm512b_kernel<4, 2><<<g, dim3(512), 0, stream>>>(
                xtbf, D_, in_bf + (size_t)i * 4718592ull, D_, xzbf, 6144, D_);
        }
        hipLaunchKernelGGL(conv_silu_kernel, dim3(2 * M_ * DI_ / 8 / 256), dim3(256), 0, stream,
                           xzbf, m_conv_w + (size_t)i * 2 * DI_ * DC_,
                           m_conv_b + (size_t)i * 2 * DI_, ucy);
        // xproj split-K: grid (2,20,16) = 640 -> shallow 256-thr (R16 config)
        g64s(ucy, DI_, xpp + (size_t)i * 2 * 128 * DI_, DI_, nullptr, nullptr, nullptr,
             part, 80, M_, 128, 192, 0, 80, 1,
             16, 8, (unsigned long long)M_ * DI_, (unsigned long long)128 * DI_,
             (unsigned long long)M_ * 80);
        hipLaunchKernelGGL(dtscan_kernel, dim3(DI_ / 256, B_, 2), dim3(256), 0, stream,
                           part, ucy, xzbf,
                           m_dt_w + (size_t)i * 2 * DI_ * DTR_, m_dt_b + (size_t)i * 2 * DI_,
                           m_Alog + (size_t)i * 2 * DI_ * DS_, m_Dp + (size_t)i * 2 * DI_);
        // out: 512-thr deep 64x64, grid (12,20,2) = 480, z = dir
        g512(ucy, DI_, out_bf + (size_t)i * 2 * D_ * DI_, DI_, nullptr, nullptr, nullptr,
             cat2b, 2 * D_, M_, D_, DI_, 0, D_, 0,
             2, 1, (unsigned long long)M_ * DI_, (unsigned long long)D_ * DI_, 768ull);
        // final (K=1536) -> xo f32
        g512(cat2b, 2 * D_, final_bf + (size_t)i * D_ * 2 * D_, 2 * D_, final_b + (size_t)i * D_,
             nullptr, nullptr, xo, D_, M_, D_, 2 * D_, 0, D_, 1, 1, 1, 0, 0, 0);
        // x = LN(xo + x); last layer also fuses the output LN -> znormb
        hipLaunchKernelGGL(ln_residual_kernel, dim3(M_), dim3(256), 0, stream,
                           xo, x, xbf, ln_g + (size_t)i * D_, ln_b + (size_t)i * D_,
                           oln_g, oln_b, znormb, (i == NL_ - 1) ? 1 : 0);
    }

    // ---------- output head (znormb filled by fused LN) ----------
    g512(znormb, D_, zout_bf, D_, zout_b, nullptr, nullptr,
         (float*)d_out, LAT_, B_ * NP_, LAT_, D_, 0, LAT_, 1, 1, 1, 0, 0, 0);
}